// Round 1
// baseline (3720.549 us; speedup 1.0000x reference)
//
#include <hip/hip_runtime.h>

#define N_NODES 50000
#define N_EDGES 800000

// ---------------------------------------------------------------------------
// GEMM: Y[N,M] = act(X)[N,K] @ W[K,M]
// One block per row. Block size = M (128 or 64, multiples of 64).
// x-row staged in LDS; each thread computes one output column.
// W[k*M + c] reads are coalesced across threads and L1/L2-resident (W <= 64KB).
// ---------------------------------------------------------------------------
template <int K, int M, bool RELU_IN>
__global__ void gemm_rowwise(const float* __restrict__ X,
                             const float* __restrict__ W,
                             float* __restrict__ Y, int N) {
    __shared__ float xs[K];
    const int row = blockIdx.x;
    if (row >= N) return;
    for (int k = threadIdx.x; k < K; k += blockDim.x) {
        float v = X[(size_t)row * K + k];
        if (RELU_IN) v = fmaxf(v, 0.0f);
        xs[k] = v;
    }
    __syncthreads();
    const int c = threadIdx.x;
    if (c < M) {
        float acc = 0.0f;
#pragma unroll 8
        for (int k = 0; k < K; ++k) {
            acc = fmaf(xs[k], W[(size_t)k * M + c], acc);
        }
        Y[(size_t)row * M + c] = acc;
    }
}

// ---------------------------------------------------------------------------
// Init aggregation buffer with the bias (so scatter can accumulate on top).
// M is a power of two (128 or 64).
// ---------------------------------------------------------------------------
template <int M>
__global__ void init_bias(float* __restrict__ Y, const float* __restrict__ b,
                          long long total) {
    long long idx = (long long)blockIdx.x * blockDim.x + threadIdx.x;
    if (idx < total) Y[idx] = b[idx & (M - 1)];
}

// ---------------------------------------------------------------------------
// Edge scatter: out[row[e], :] += val[e] * S[col[e], :]
// Each thread handles 4 consecutive features of one edge (float4 gather,
// 4 scalar fp32 atomicAdds — device-scope by default on CDNA).
// ---------------------------------------------------------------------------
template <int M>
__global__ void scatter_edges(const float* __restrict__ S,
                              const int* __restrict__ erow,
                              const int* __restrict__ ecol,
                              const float* __restrict__ eval,
                              float* __restrict__ out) {
    constexpr int PER_EDGE = M / 4;
    long long gid = (long long)blockIdx.x * blockDim.x + threadIdx.x;
    int e = (int)(gid / PER_EDGE);
    int f = (int)(gid % PER_EDGE) * 4;
    if (e >= N_EDGES) return;
    const int r = erow[e];
    const int c = ecol[e];
    const float v = eval[e];
    const float4 s = *reinterpret_cast<const float4*>(S + (size_t)c * M + f);
    float* o = out + (size_t)r * M + f;
    atomicAdd(o + 0, v * s.x);
    atomicAdd(o + 1, v * s.y);
    atomicAdd(o + 2, v * s.z);
    atomicAdd(o + 3, v * s.w);
}

extern "C" void kernel_launch(void* const* d_in, const int* in_sizes, int n_in,
                              void* d_out, int out_size, void* d_ws, size_t ws_size,
                              hipStream_t stream) {
    const float* x    = (const float*)d_in[0];
    const int*   erow = (const int*)d_in[1];
    const int*   ecol = (const int*)d_in[2];
    const float* eval = (const float*)d_in[3];
    const float* W1   = (const float*)d_in[4];
    const float* b1   = (const float*)d_in[5];
    const float* W2   = (const float*)d_in[6];
    const float* b2   = (const float*)d_in[7];
    const float* W3   = (const float*)d_in[8];
    const float* b3   = (const float*)d_in[9];
    float* out = (float*)d_out;

    // Workspace layout: A = support buffer [N,128], B = hidden buffer [N,128]
    float* A = (float*)d_ws;
    float* B = A + (size_t)N_NODES * 128;

    const long long tot128 = (long long)N_NODES * 128;
    const int blk = 256;

    // ---- Layer 1: h1 = relu(spmm(x @ W1) + b1)  (relu deferred to L2 gemm)
    gemm_rowwise<128, 128, false><<<N_NODES, 128, 0, stream>>>(x, W1, A, N_NODES);
    init_bias<128><<<(int)((tot128 + blk - 1) / blk), blk, 0, stream>>>(B, b1, tot128);
    {
        long long nthreads = (long long)N_EDGES * (128 / 4);
        scatter_edges<128><<<(int)((nthreads + blk - 1) / blk), blk, 0, stream>>>(
            A, erow, ecol, eval, B);
    }

    // ---- Layer 2: h2 = relu(spmm(relu(h1) @ W2) + b2) (input relu fused)
    gemm_rowwise<128, 128, true><<<N_NODES, 128, 0, stream>>>(B, W2, A, N_NODES);
    init_bias<128><<<(int)((tot128 + blk - 1) / blk), blk, 0, stream>>>(B, b2, tot128);
    {
        long long nthreads = (long long)N_EDGES * (128 / 4);
        scatter_edges<128><<<(int)((nthreads + blk - 1) / blk), blk, 0, stream>>>(
            A, erow, ecol, eval, B);
    }

    // ---- Layer 3: out = spmm(relu(h2) @ W3) + b3 (no activation)
    gemm_rowwise<128, 64, true><<<N_NODES, 64, 0, stream>>>(B, W3, A, N_NODES);
    {
        const long long tot64 = (long long)N_NODES * 64;
        init_bias<64><<<(int)((tot64 + blk - 1) / blk), blk, 0, stream>>>(out, b3, tot64);
        long long nthreads = (long long)N_EDGES * (64 / 4);
        scatter_edges<64><<<(int)((nthreads + blk - 1) / blk), blk, 0, stream>>>(
            A, erow, ecol, eval, out);
    }
}

// Round 2
// 693.098 us; speedup vs baseline: 5.3680x; 5.3680x over previous
//
#include <hip/hip_runtime.h>

#define N_NODES 50000
#define N_EDGES 800000

// ---------------------------------------------------------------------------
// GEMM: Y[N,M] = act(X)[N,K] @ W[K,M]   (one block per row; W via L1/L2)
// ---------------------------------------------------------------------------
template <int K, int M, bool RELU_IN>
__global__ void gemm_rowwise(const float* __restrict__ X,
                             const float* __restrict__ W,
                             float* __restrict__ Y, int N) {
    __shared__ float xs[K];
    const int row = blockIdx.x;
    if (row >= N) return;
    for (int k = threadIdx.x; k < K; k += blockDim.x) {
        float v = X[(size_t)row * K + k];
        if (RELU_IN) v = fmaxf(v, 0.0f);
        xs[k] = v;
    }
    __syncthreads();
    const int c = threadIdx.x;
    if (c < M) {
        float acc = 0.0f;
#pragma unroll 8
        for (int k = 0; k < K; ++k) {
            acc = fmaf(xs[k], W[(size_t)k * M + c], acc);
        }
        Y[(size_t)row * M + c] = acc;
    }
}

// ---------------------------------------------------------------------------
// CSR build: zero degrees -> histogram -> single-block scan -> slot fill
// ---------------------------------------------------------------------------
__global__ void zero_ints(int* __restrict__ p, int n) {
    int i = blockIdx.x * blockDim.x + threadIdx.x;
    if (i < n) p[i] = 0;
}

__global__ void degree_histogram(const int* __restrict__ erow, int* __restrict__ deg) {
    int e = blockIdx.x * blockDim.x + threadIdx.x;
    if (e < N_EDGES) atomicAdd(&deg[erow[e]], 1);
}

// One block of 1024 threads scans all N degrees into row_ptr (exclusive) and
// seeds cursor with the same values. row_ptr[n] = total.
__global__ void scan_rowptr(const int* __restrict__ deg, int* __restrict__ rptr,
                            int* __restrict__ cursor, int n) {
    __shared__ int sums[1024];
    const int T = 1024;
    const int t = threadIdx.x;
    const int chunk = (n + T - 1) / T;
    const int beg = t * chunk;
    const int end = min(beg + chunk, n);
    int s = 0;
    for (int i = beg; i < end; ++i) s += deg[i];
    sums[t] = s;
    __syncthreads();
    for (int off = 1; off < T; off <<= 1) {
        int v = 0;
        if (t >= off) v = sums[t - off];
        __syncthreads();
        sums[t] += v;
        __syncthreads();
    }
    int run = sums[t] - s;  // exclusive prefix of this thread's chunk
    for (int i = beg; i < end; ++i) {
        rptr[i] = run;
        cursor[i] = run;
        run += deg[i];
    }
    if (t == T - 1) rptr[n] = run;  // last thread's chunk covers (or is past) n
}

__global__ void fill_csr(const int* __restrict__ erow, const int* __restrict__ ecol,
                         const float* __restrict__ eval, int* __restrict__ cursor,
                         int* __restrict__ ccol, float* __restrict__ cval) {
    int e = blockIdx.x * blockDim.x + threadIdx.x;
    if (e >= N_EDGES) return;
    int slot = atomicAdd(&cursor[erow[e]], 1);
    ccol[slot] = ecol[e];
    cval[slot] = eval[e];
}

// ---------------------------------------------------------------------------
// CSR aggregation: out[i,:] = b[:] + sum_j val[j] * S[col[j],:]
// M/4 lanes per node, float4 accumulator per lane. Writes each output once.
// ---------------------------------------------------------------------------
template <int M>
__global__ void aggregate_csr(const float* __restrict__ S,
                              const int* __restrict__ rptr,
                              const int* __restrict__ ccol,
                              const float* __restrict__ cval,
                              const float* __restrict__ bias,
                              float* __restrict__ out, int N) {
    constexpr int TPN = M / 4;  // threads per node
    const int npb = blockDim.x / TPN;
    const int node = blockIdx.x * npb + threadIdx.x / TPN;
    const int f4 = threadIdx.x % TPN;
    if (node >= N) return;
    const int beg = rptr[node];
    const int end = rptr[node + 1];
    float4 acc = *reinterpret_cast<const float4*>(bias + f4 * 4);
    for (int j = beg; j < end; ++j) {
        const int c = ccol[j];
        const float v = cval[j];
        const float4 s = *reinterpret_cast<const float4*>(S + (size_t)c * M + f4 * 4);
        acc.x = fmaf(v, s.x, acc.x);
        acc.y = fmaf(v, s.y, acc.y);
        acc.z = fmaf(v, s.z, acc.z);
        acc.w = fmaf(v, s.w, acc.w);
    }
    *reinterpret_cast<float4*>(out + (size_t)node * M + f4 * 4) = acc;
}

// ---------------------------------------------------------------------------
// Fallback (round-1 proven path) if ws_size is too small for CSR arrays.
// ---------------------------------------------------------------------------
template <int M>
__global__ void init_bias(float* __restrict__ Y, const float* __restrict__ b,
                          long long total) {
    long long idx = (long long)blockIdx.x * blockDim.x + threadIdx.x;
    if (idx < total) Y[idx] = b[idx & (M - 1)];
}

template <int M>
__global__ void scatter_edges(const float* __restrict__ S,
                              const int* __restrict__ erow,
                              const int* __restrict__ ecol,
                              const float* __restrict__ eval,
                              float* __restrict__ out) {
    constexpr int PER_EDGE = M / 4;
    long long gid = (long long)blockIdx.x * blockDim.x + threadIdx.x;
    int e = (int)(gid / PER_EDGE);
    int f = (int)(gid % PER_EDGE) * 4;
    if (e >= N_EDGES) return;
    const int r = erow[e];
    const int c = ecol[e];
    const float v = eval[e];
    const float4 s = *reinterpret_cast<const float4*>(S + (size_t)c * M + f);
    float* o = out + (size_t)r * M + f;
    atomicAdd(o + 0, v * s.x);
    atomicAdd(o + 1, v * s.y);
    atomicAdd(o + 2, v * s.z);
    atomicAdd(o + 3, v * s.w);
}

extern "C" void kernel_launch(void* const* d_in, const int* in_sizes, int n_in,
                              void* d_out, int out_size, void* d_ws, size_t ws_size,
                              hipStream_t stream) {
    const float* x    = (const float*)d_in[0];
    const int*   erow = (const int*)d_in[1];
    const int*   ecol = (const int*)d_in[2];
    const float* eval = (const float*)d_in[3];
    const float* W1   = (const float*)d_in[4];
    const float* b1   = (const float*)d_in[5];
    const float* W2   = (const float*)d_in[6];
    const float* b2   = (const float*)d_in[7];
    const float* W3   = (const float*)d_in[8];
    const float* b3   = (const float*)d_in[9];
    float* out = (float*)d_out;

    const size_t nodes_f = (size_t)N_NODES * 128;
    float* A = (float*)d_ws;            // [N,128] gemm output / gather source
    float* B = A + nodes_f;             // [N,128] aggregation target (layers 1,2)
    int*   deg    = (int*)(B + nodes_f);
    int*   rptr   = deg + N_NODES;          // N_NODES+1 entries
    int*   cursor = rptr + (N_NODES + 1);
    int*   ccol   = cursor + N_NODES;       // N_EDGES
    float* cval   = (float*)(ccol + N_EDGES);

    const size_t needed = ((char*)(cval + N_EDGES)) - ((char*)d_ws);
    const int blk = 256;

    if (ws_size >= needed) {
        // ---- Build CSR (once; reused by all 3 layers)
        zero_ints<<<(N_NODES + blk - 1) / blk, blk, 0, stream>>>(deg, N_NODES);
        degree_histogram<<<(N_EDGES + blk - 1) / blk, blk, 0, stream>>>(erow, deg);
        scan_rowptr<<<1, 1024, 0, stream>>>(deg, rptr, cursor, N_NODES);
        fill_csr<<<(N_EDGES + blk - 1) / blk, blk, 0, stream>>>(erow, ecol, eval,
                                                                cursor, ccol, cval);

        // ---- Layer 1
        gemm_rowwise<128, 128, false><<<N_NODES, 128, 0, stream>>>(x, W1, A, N_NODES);
        aggregate_csr<128><<<(N_NODES * 32 + blk - 1) / blk, blk, 0, stream>>>(
            A, rptr, ccol, cval, b1, B, N_NODES);

        // ---- Layer 2 (input ReLU fused into gemm read)
        gemm_rowwise<128, 128, true><<<N_NODES, 128, 0, stream>>>(B, W2, A, N_NODES);
        aggregate_csr<128><<<(N_NODES * 32 + blk - 1) / blk, blk, 0, stream>>>(
            A, rptr, ccol, cval, b2, B, N_NODES);

        // ---- Layer 3
        gemm_rowwise<128, 64, true><<<N_NODES, 64, 0, stream>>>(B, W3, A, N_NODES);
        aggregate_csr<64><<<(N_NODES * 16 + blk - 1) / blk, blk, 0, stream>>>(
            A, rptr, ccol, cval, b3, out, N_NODES);
    } else {
        // ---- Fallback: round-1 atomic path
        const long long tot128 = (long long)N_NODES * 128;
        gemm_rowwise<128, 128, false><<<N_NODES, 128, 0, stream>>>(x, W1, A, N_NODES);
        init_bias<128><<<(int)((tot128 + blk - 1) / blk), blk, 0, stream>>>(B, b1, tot128);
        scatter_edges<128><<<(int)(((long long)N_EDGES * 32 + blk - 1) / blk), blk, 0,
                             stream>>>(A, erow, ecol, eval, B);
        gemm_rowwise<128, 128, true><<<N_NODES, 128, 0, stream>>>(B, W2, A, N_NODES);
        init_bias<128><<<(int)((tot128 + blk - 1) / blk), blk, 0, stream>>>(B, b2, tot128);
        scatter_edges<128><<<(int)(((long long)N_EDGES * 32 + blk - 1) / blk), blk, 0,
                             stream>>>(A, erow, ecol, eval, B);
        gemm_rowwise<128, 64, true><<<N_NODES, 64, 0, stream>>>(B, W3, A, N_NODES);
        const long long tot64 = (long long)N_NODES * 64;
        init_bias<64><<<(int)((tot64 + blk - 1) / blk), blk, 0, stream>>>(out, b3, tot64);
        scatter_edges<64><<<(int)(((long long)N_EDGES * 16 + blk - 1) / blk), blk, 0,
                            stream>>>(A, erow, ecol, eval, out);
    }
}

// Round 3
// 507.223 us; speedup vs baseline: 7.3351x; 1.3665x over previous
//
#include <hip/hip_runtime.h>

#define N_NODES 50000
#define N_EDGES 800000

typedef __attribute__((ext_vector_type(4))) float f32x4;
typedef __attribute__((ext_vector_type(8))) short bf16x8;

__device__ inline unsigned short f32_to_bf16(float f) {
    unsigned int u = __builtin_bit_cast(unsigned int, f);
    u += 0x7FFF + ((u >> 16) & 1);  // RNE
    return (unsigned short)(u >> 16);
}
__device__ inline float bf16_to_f32(unsigned short h) {
    unsigned int u = ((unsigned int)h) << 16;
    return __builtin_bit_cast(float, u);
}

// ---------------------------------------------------------------------------
// fp32 -> bf16 elementwise (float4 in, 4x bf16 out)
// ---------------------------------------------------------------------------
__global__ void convert_f32_bf16(const float* __restrict__ in,
                                 unsigned short* __restrict__ out, long long n4) {
    long long i = (long long)blockIdx.x * blockDim.x + threadIdx.x;
    if (i >= n4) return;
    float4 v = reinterpret_cast<const float4*>(in)[i];
    ushort4 o;
    o.x = f32_to_bf16(v.x); o.y = f32_to_bf16(v.y);
    o.z = f32_to_bf16(v.z); o.w = f32_to_bf16(v.w);
    reinterpret_cast<ushort4*>(out)[i] = o;
}

// W[K][M] fp32 -> Wt[M][K] bf16 (single block; tiny)
template <int K, int M>
__global__ void convert_w_t(const float* __restrict__ W,
                            unsigned short* __restrict__ Wt) {
    for (int idx = threadIdx.x; idx < K * M; idx += blockDim.x) {
        int k = idx / M, m = idx % M;
        Wt[m * K + k] = f32_to_bf16(W[idx]);
    }
}

// ---------------------------------------------------------------------------
// CSR build (unchanged from round 2 — proven)
// ---------------------------------------------------------------------------
__global__ void zero_ints(int* __restrict__ p, int n) {
    int i = blockIdx.x * blockDim.x + threadIdx.x;
    if (i < n) p[i] = 0;
}

__global__ void degree_histogram(const int* __restrict__ erow, int* __restrict__ deg) {
    int e = blockIdx.x * blockDim.x + threadIdx.x;
    if (e < N_EDGES) atomicAdd(&deg[erow[e]], 1);
}

__global__ void scan_rowptr(const int* __restrict__ deg, int* __restrict__ rptr,
                            int* __restrict__ cursor, int n) {
    __shared__ int sums[1024];
    const int T = 1024;
    const int t = threadIdx.x;
    const int chunk = (n + T - 1) / T;
    const int beg = t * chunk;
    const int end = min(beg + chunk, n);
    int s = 0;
    for (int i = beg; i < end; ++i) s += deg[i];
    sums[t] = s;
    __syncthreads();
    for (int off = 1; off < T; off <<= 1) {
        int v = 0;
        if (t >= off) v = sums[t - off];
        __syncthreads();
        sums[t] += v;
        __syncthreads();
    }
    int run = sums[t] - s;
    for (int i = beg; i < end; ++i) {
        rptr[i] = run;
        cursor[i] = run;
        run += deg[i];
    }
    if (t == T - 1) rptr[n] = run;
}

__global__ void fill_csr(const int* __restrict__ erow, const int* __restrict__ ecol,
                         const float* __restrict__ eval, int* __restrict__ cursor,
                         int* __restrict__ ccol, float* __restrict__ cval) {
    int e = blockIdx.x * blockDim.x + threadIdx.x;
    if (e >= N_EDGES) return;
    int slot = atomicAdd(&cursor[erow[e]], 1);
    ccol[slot] = ecol[e];
    cval[slot] = eval[e];
}

// ---------------------------------------------------------------------------
// MFMA GEMM: Y[N,NOUT] = Xb[N,128](bf16) @ W (staged transposed, bf16)
// 64 rows/block, 4 waves; wave w computes rows [w*16, w*16+16) x all NOUT cols.
// LDS rows padded +8 bf16 (16B) -> uniform bank spread for ds_read_b128.
// Fragment layouts [measured m89/m91/m120]:
//   A[m=lane&15][k=quad*8+j], B[k=quad*8+j][n=lane&15] (from Wt[n][k]),
//   C row=quad*4+reg, col=lane&15.
// ---------------------------------------------------------------------------
template <int NOUT, bool OUT_BF16>
__global__ __launch_bounds__(256) void gemm_mfma(
    const unsigned short* __restrict__ Xb, const unsigned short* __restrict__ Wt,
    void* __restrict__ Yv, int N) {
    constexpr int K = 128;
    constexpr int KP = K + 8;   // padded LDS row (272 B)
    constexpr int NT = NOUT / 16;
    __shared__ unsigned short Xs[64 * KP];
    __shared__ unsigned short Ws[NOUT * KP];

    const int tid = threadIdx.x;
    const int block_row = blockIdx.x * 64;

    // stage X tile: 64 rows x 16 chunks of 16B (clamp OOB rows; store-guarded)
    for (int idx = tid; idx < 64 * 16; idx += 256) {
        int r = idx >> 4, ch = idx & 15;
        int gr = block_row + r;
        if (gr >= N) gr = N - 1;
        uint4 v = *reinterpret_cast<const uint4*>(Xb + (size_t)gr * K + ch * 8);
        *reinterpret_cast<uint4*>(Xs + r * KP + ch * 8) = v;
    }
    // stage Wt: NOUT rows x 16 chunks of 16B
    for (int idx = tid; idx < NOUT * 16; idx += 256) {
        int r = idx >> 4, ch = idx & 15;
        uint4 v = *reinterpret_cast<const uint4*>(Wt + r * K + ch * 8);
        *reinterpret_cast<uint4*>(Ws + r * KP + ch * 8) = v;
    }
    __syncthreads();

    const int wave = tid >> 6;
    const int lane = tid & 63;
    const int m = lane & 15;
    const int quad = lane >> 4;
    const int rowbase = wave * 16;

    f32x4 acc[NT];
#pragma unroll
    for (int t = 0; t < NT; ++t) acc[t] = (f32x4){0.f, 0.f, 0.f, 0.f};

#pragma unroll
    for (int kt = 0; kt < 4; ++kt) {
        bf16x8 a = *reinterpret_cast<const bf16x8*>(Xs + (rowbase + m) * KP + kt * 32 + quad * 8);
#pragma unroll
        for (int t = 0; t < NT; ++t) {
            bf16x8 b = *reinterpret_cast<const bf16x8*>(Ws + (t * 16 + m) * KP + kt * 32 + quad * 8);
            acc[t] = __builtin_amdgcn_mfma_f32_16x16x32_bf16(a, b, acc[t], 0, 0, 0);
        }
    }

#pragma unroll
    for (int t = 0; t < NT; ++t) {
#pragma unroll
        for (int r = 0; r < 4; ++r) {
            int grow = block_row + rowbase + quad * 4 + r;
            if (grow < N) {
                if (OUT_BF16)
                    reinterpret_cast<unsigned short*>(Yv)[(size_t)grow * NOUT + t * 16 + m] =
                        f32_to_bf16(acc[t][r]);
                else
                    reinterpret_cast<float*>(Yv)[(size_t)grow * NOUT + t * 16 + m] = acc[t][r];
            }
        }
    }
}

// ---------------------------------------------------------------------------
// CSR aggregation from bf16 source, fused bias + ReLU, bf16 output.
// 16 lanes/node, 8 features/lane (uint4 = 8 bf16 per gather).
// ---------------------------------------------------------------------------
__global__ void aggregate_bf16(const unsigned short* __restrict__ S,
                               const int* __restrict__ rptr,
                               const int* __restrict__ ccol,
                               const float* __restrict__ cval,
                               const float* __restrict__ bias,
                               unsigned short* __restrict__ outb, int N) {
    const int node = blockIdx.x * (blockDim.x / 16) + threadIdx.x / 16;
    const int f8 = threadIdx.x & 15;
    if (node >= N) return;
    const int beg = rptr[node];
    const int end = rptr[node + 1];
    float acc[8];
#pragma unroll
    for (int i = 0; i < 8; ++i) acc[i] = bias[f8 * 8 + i];
    for (int j = beg; j < end; ++j) {
        const int c = ccol[j];
        const float v = cval[j];
        uint4 s = *reinterpret_cast<const uint4*>(S + (size_t)c * 128 + f8 * 8);
        const unsigned short* sp = reinterpret_cast<const unsigned short*>(&s);
#pragma unroll
        for (int i = 0; i < 8; ++i) acc[i] = fmaf(v, bf16_to_f32(sp[i]), acc[i]);
    }
    unsigned short o[8];
#pragma unroll
    for (int i = 0; i < 8; ++i) o[i] = f32_to_bf16(fmaxf(acc[i], 0.0f));
    *reinterpret_cast<uint4*>(outb + (size_t)node * 128 + f8 * 8) =
        *reinterpret_cast<uint4*>(o);
}

// ---------------------------------------------------------------------------
// Layer-3 CSR aggregation: fp32 source, + bias, no activation, fp32 out.
// 16 lanes/node, float4 per lane (M=64).
// ---------------------------------------------------------------------------
__global__ void aggregate_f32_64(const float* __restrict__ S,
                                 const int* __restrict__ rptr,
                                 const int* __restrict__ ccol,
                                 const float* __restrict__ cval,
                                 const float* __restrict__ bias,
                                 float* __restrict__ out, int N) {
    const int node = blockIdx.x * (blockDim.x / 16) + threadIdx.x / 16;
    const int f4 = threadIdx.x & 15;
    if (node >= N) return;
    const int beg = rptr[node];
    const int end = rptr[node + 1];
    float4 acc = *reinterpret_cast<const float4*>(bias + f4 * 4);
    for (int j = beg; j < end; ++j) {
        const int c = ccol[j];
        const float v = cval[j];
        const float4 s = *reinterpret_cast<const float4*>(S + (size_t)c * 64 + f4 * 4);
        acc.x = fmaf(v, s.x, acc.x);
        acc.y = fmaf(v, s.y, acc.y);
        acc.z = fmaf(v, s.z, acc.z);
        acc.w = fmaf(v, s.w, acc.w);
    }
    *reinterpret_cast<float4*>(out + (size_t)node * 64 + f4 * 4) = acc;
}

extern "C" void kernel_launch(void* const* d_in, const int* in_sizes, int n_in,
                              void* d_out, int out_size, void* d_ws, size_t ws_size,
                              hipStream_t stream) {
    const float* x    = (const float*)d_in[0];
    const int*   erow = (const int*)d_in[1];
    const int*   ecol = (const int*)d_in[2];
    const float* eval = (const float*)d_in[3];
    const float* W1   = (const float*)d_in[4];
    const float* b1   = (const float*)d_in[5];
    const float* W2   = (const float*)d_in[6];
    const float* b2   = (const float*)d_in[7];
    const float* W3   = (const float*)d_in[8];
    const float* b3   = (const float*)d_in[9];
    float* out = (float*)d_out;

    // Workspace layout (all 16B-aligned):
    //   Xb [N,128] bf16  — layer input (x, then reused as H between layers)
    //   Ab [N,128] bf16  — GEMM support output; reused as fp32 [N,64] in layer 3
    //   Wt1/Wt2 [128,128] bf16, Wt3 [64,128] bf16 — transposed weights
    //   CSR: deg, rptr, cursor, ccol (int), cval (float)
    const size_t nf = (size_t)N_NODES * 128;
    unsigned short* Xb  = (unsigned short*)d_ws;
    unsigned short* Ab  = Xb + nf;
    unsigned short* Wt1 = Ab + nf;
    unsigned short* Wt2 = Wt1 + 128 * 128;
    unsigned short* Wt3 = Wt2 + 128 * 128;
    int*   deg    = (int*)(Wt3 + 64 * 128);
    int*   rptr   = deg + N_NODES;
    int*   cursor = rptr + (N_NODES + 1);
    int*   ccol   = cursor + N_NODES;
    float* cval   = (float*)(ccol + N_EDGES);
    float* Af     = (float*)Ab;  // layer-3 fp32 support [N,64]

    const int blk = 256;
    const int gemm_grid = (N_NODES + 63) / 64;
    const int agg_grid = (N_NODES * 16 + blk - 1) / blk;  // 16 lanes/node

    // ---- precompute: conversions + CSR
    {
        long long n4 = nf / 4;
        convert_f32_bf16<<<(int)((n4 + blk - 1) / blk), blk, 0, stream>>>(x, Xb, n4);
    }
    convert_w_t<128, 128><<<1, 256, 0, stream>>>(W1, Wt1);
    convert_w_t<128, 128><<<1, 256, 0, stream>>>(W2, Wt2);
    convert_w_t<128, 64><<<1, 256, 0, stream>>>(W3, Wt3);
    zero_ints<<<(N_NODES + blk - 1) / blk, blk, 0, stream>>>(deg, N_NODES);
    degree_histogram<<<(N_EDGES + blk - 1) / blk, blk, 0, stream>>>(erow, deg);
    scan_rowptr<<<1, 1024, 0, stream>>>(deg, rptr, cursor, N_NODES);
    fill_csr<<<(N_EDGES + blk - 1) / blk, blk, 0, stream>>>(erow, ecol, eval,
                                                            cursor, ccol, cval);

    // ---- Layer 1
    gemm_mfma<128, true><<<gemm_grid, 256, 0, stream>>>(Xb, Wt1, Ab, N_NODES);
    aggregate_bf16<<<agg_grid, blk, 0, stream>>>(Ab, rptr, ccol, cval, b1, Xb, N_NODES);

    // ---- Layer 2
    gemm_mfma<128, true><<<gemm_grid, 256, 0, stream>>>(Xb, Wt2, Ab, N_NODES);
    aggregate_bf16<<<agg_grid, blk, 0, stream>>>(Ab, rptr, ccol, cval, b2, Xb, N_NODES);

    // ---- Layer 3 (fp32 support + fp32 aggregation into d_out)
    gemm_mfma<64, false><<<gemm_grid, 256, 0, stream>>>(Xb, Wt3, Af, N_NODES);
    aggregate_f32_64<<<agg_grid, blk, 0, stream>>>(Af, rptr, ccol, cval, b3, out, N_NODES);
}

// Round 4
// 361.458 us; speedup vs baseline: 10.2932x; 1.4033x over previous
//
#include <hip/hip_runtime.h>

#define N_NODES 50000
#define N_EDGES 800000
#define SCAN_TILE 2048  // 256 threads x 8 elems

typedef __attribute__((ext_vector_type(4))) float f32x4;
typedef __attribute__((ext_vector_type(8))) short bf16x8;

__device__ inline unsigned short f32_to_bf16(float f) {
    unsigned int u = __builtin_bit_cast(unsigned int, f);
    u += 0x7FFF + ((u >> 16) & 1);  // RNE
    return (unsigned short)(u >> 16);
}
__device__ inline float bf16_to_f32(unsigned short h) {
    unsigned int u = ((unsigned int)h) << 16;
    return __builtin_bit_cast(float, u);
}

// ---------------------------------------------------------------------------
// fp32 -> bf16 elementwise (float4 in, 4x bf16 out)
// ---------------------------------------------------------------------------
__global__ void convert_f32_bf16(const float* __restrict__ in,
                                 unsigned short* __restrict__ out, long long n4) {
    long long i = (long long)blockIdx.x * blockDim.x + threadIdx.x;
    if (i >= n4) return;
    float4 v = reinterpret_cast<const float4*>(in)[i];
    ushort4 o;
    o.x = f32_to_bf16(v.x); o.y = f32_to_bf16(v.y);
    o.z = f32_to_bf16(v.z); o.w = f32_to_bf16(v.w);
    reinterpret_cast<ushort4*>(out)[i] = o;
}

// W[K][M] fp32 -> Wt[M][K] bf16 (grid-parallel)
template <int K, int M>
__global__ void convert_w_t(const float* __restrict__ W,
                            unsigned short* __restrict__ Wt) {
    int idx = blockIdx.x * blockDim.x + threadIdx.x;
    if (idx >= K * M) return;
    int k = idx / M, m = idx % M;
    Wt[m * K + k] = f32_to_bf16(W[idx]);
}

// ---------------------------------------------------------------------------
// CSR build: zero -> histogram -> two-kernel multi-block scan -> slot fill
// ---------------------------------------------------------------------------
__global__ void zero_ints(int* __restrict__ p, int n) {
    int i = blockIdx.x * blockDim.x + threadIdx.x;
    if (i < n) p[i] = 0;
}

__global__ void degree_histogram(const int* __restrict__ erow, int* __restrict__ deg) {
    int e = blockIdx.x * blockDim.x + threadIdx.x;
    if (e < N_EDGES) atomicAdd(&deg[erow[e]], 1);
}

// Tile-local exclusive scan: each block scans SCAN_TILE elems (8/thread),
// writes per-element exclusive prefixes (tile-local) and the tile total.
__global__ void scan_tiles(const int* __restrict__ deg, int* __restrict__ local,
                           int* __restrict__ tsum, int n) {
    __shared__ int sums[256];
    const int t = threadIdx.x;
    const int base = blockIdx.x * SCAN_TILE + t * 8;
    int v[8];
    int s = 0;
#pragma unroll
    for (int i = 0; i < 8; ++i) {
        v[i] = (base + i < n) ? deg[base + i] : 0;
        s += v[i];
    }
    sums[t] = s;
    __syncthreads();
    for (int off = 1; off < 256; off <<= 1) {
        int x = (t >= off) ? sums[t - off] : 0;
        __syncthreads();
        sums[t] += x;
        __syncthreads();
    }
    int run = sums[t] - s;  // exclusive prefix of this thread within tile
#pragma unroll
    for (int i = 0; i < 8; ++i) {
        if (base + i < n) local[base + i] = run;
        run += v[i];
    }
    if (t == 255) tsum[blockIdx.x] = run;  // tile total
}

// Add per-tile offsets (tiny scalar loop over tile totals, once per block),
// emit rptr and cursor; block 0 also writes rptr[n].
__global__ void scan_finalize(const int* __restrict__ local,
                              const int* __restrict__ tsum, int ntiles,
                              int* __restrict__ rptr, int* __restrict__ cursor,
                              int n) {
    __shared__ int off_s;
    const int b = blockIdx.x;
    if (threadIdx.x == 0) {
        int s = 0;
        for (int i = 0; i < b; ++i) s += tsum[i];
        off_s = s;
        if (b == 0) {
            int tot = 0;
            for (int i = 0; i < ntiles; ++i) tot += tsum[i];
            rptr[n] = tot;
        }
    }
    __syncthreads();
    const int off = off_s;
    const int base = b * SCAN_TILE + threadIdx.x * 8;
#pragma unroll
    for (int i = 0; i < 8; ++i) {
        int idx = base + i;
        if (idx < n) {
            int v = local[idx] + off;
            rptr[idx] = v;
            cursor[idx] = v;
        }
    }
}

__global__ void fill_csr(const int* __restrict__ erow, const int* __restrict__ ecol,
                         const float* __restrict__ eval, int* __restrict__ cursor,
                         int* __restrict__ ccol, float* __restrict__ cval) {
    int e = blockIdx.x * blockDim.x + threadIdx.x;
    if (e >= N_EDGES) return;
    int slot = atomicAdd(&cursor[erow[e]], 1);
    ccol[slot] = ecol[e];
    cval[slot] = eval[e];
}

// ---------------------------------------------------------------------------
// MFMA GEMM: Y[N,NOUT] = Xb[N,128](bf16) @ W (staged transposed, bf16)
// 64 rows/block, 4 waves. Fragment layouts [measured m89/m91/m120].
// ---------------------------------------------------------------------------
template <int NOUT, bool OUT_BF16>
__global__ __launch_bounds__(256) void gemm_mfma(
    const unsigned short* __restrict__ Xb, const unsigned short* __restrict__ Wt,
    void* __restrict__ Yv, int N) {
    constexpr int K = 128;
    constexpr int KP = K + 8;   // padded LDS row (272 B)
    constexpr int NT = NOUT / 16;
    __shared__ unsigned short Xs[64 * KP];
    __shared__ unsigned short Ws[NOUT * KP];

    const int tid = threadIdx.x;
    const int block_row = blockIdx.x * 64;

    for (int idx = tid; idx < 64 * 16; idx += 256) {
        int r = idx >> 4, ch = idx & 15;
        int gr = block_row + r;
        if (gr >= N) gr = N - 1;
        uint4 v = *reinterpret_cast<const uint4*>(Xb + (size_t)gr * K + ch * 8);
        *reinterpret_cast<uint4*>(Xs + r * KP + ch * 8) = v;
    }
    for (int idx = tid; idx < NOUT * 16; idx += 256) {
        int r = idx >> 4, ch = idx & 15;
        uint4 v = *reinterpret_cast<const uint4*>(Wt + r * K + ch * 8);
        *reinterpret_cast<uint4*>(Ws + r * KP + ch * 8) = v;
    }
    __syncthreads();

    const int wave = tid >> 6;
    const int lane = tid & 63;
    const int m = lane & 15;
    const int quad = lane >> 4;
    const int rowbase = wave * 16;

    f32x4 acc[NT];
#pragma unroll
    for (int t = 0; t < NT; ++t) acc[t] = (f32x4){0.f, 0.f, 0.f, 0.f};

#pragma unroll
    for (int kt = 0; kt < 4; ++kt) {
        bf16x8 a = *reinterpret_cast<const bf16x8*>(Xs + (rowbase + m) * KP + kt * 32 + quad * 8);
#pragma unroll
        for (int t = 0; t < NT; ++t) {
            bf16x8 b = *reinterpret_cast<const bf16x8*>(Ws + (t * 16 + m) * KP + kt * 32 + quad * 8);
            acc[t] = __builtin_amdgcn_mfma_f32_16x16x32_bf16(a, b, acc[t], 0, 0, 0);
        }
    }

#pragma unroll
    for (int t = 0; t < NT; ++t) {
#pragma unroll
        for (int r = 0; r < 4; ++r) {
            int grow = block_row + rowbase + quad * 4 + r;
            if (grow < N) {
                if (OUT_BF16)
                    reinterpret_cast<unsigned short*>(Yv)[(size_t)grow * NOUT + t * 16 + m] =
                        f32_to_bf16(acc[t][r]);
                else
                    reinterpret_cast<float*>(Yv)[(size_t)grow * NOUT + t * 16 + m] = acc[t][r];
            }
        }
    }
}

// ---------------------------------------------------------------------------
// CSR aggregation from bf16 source, fused bias + ReLU, bf16 output.
// ---------------------------------------------------------------------------
__global__ void aggregate_bf16(const unsigned short* __restrict__ S,
                               const int* __restrict__ rptr,
                               const int* __restrict__ ccol,
                               const float* __restrict__ cval,
                               const float* __restrict__ bias,
                               unsigned short* __restrict__ outb, int N) {
    const int node = blockIdx.x * (blockDim.x / 16) + threadIdx.x / 16;
    const int f8 = threadIdx.x & 15;
    if (node >= N) return;
    const int beg = rptr[node];
    const int end = rptr[node + 1];
    float acc[8];
#pragma unroll
    for (int i = 0; i < 8; ++i) acc[i] = bias[f8 * 8 + i];
    for (int j = beg; j < end; ++j) {
        const int c = ccol[j];
        const float v = cval[j];
        uint4 s = *reinterpret_cast<const uint4*>(S + (size_t)c * 128 + f8 * 8);
        const unsigned short* sp = reinterpret_cast<const unsigned short*>(&s);
#pragma unroll
        for (int i = 0; i < 8; ++i) acc[i] = fmaf(v, bf16_to_f32(sp[i]), acc[i]);
    }
    unsigned short o[8];
#pragma unroll
    for (int i = 0; i < 8; ++i) o[i] = f32_to_bf16(fmaxf(acc[i], 0.0f));
    *reinterpret_cast<uint4*>(outb + (size_t)node * 128 + f8 * 8) =
        *reinterpret_cast<uint4*>(o);
}

// ---------------------------------------------------------------------------
// Layer-3 CSR aggregation: fp32 source, + bias, no activation, fp32 out.
// ---------------------------------------------------------------------------
__global__ void aggregate_f32_64(const float* __restrict__ S,
                                 const int* __restrict__ rptr,
                                 const int* __restrict__ ccol,
                                 const float* __restrict__ cval,
                                 const float* __restrict__ bias,
                                 float* __restrict__ out, int N) {
    const int node = blockIdx.x * (blockDim.x / 16) + threadIdx.x / 16;
    const int f4 = threadIdx.x & 15;
    if (node >= N) return;
    const int beg = rptr[node];
    const int end = rptr[node + 1];
    float4 acc = *reinterpret_cast<const float4*>(bias + f4 * 4);
    for (int j = beg; j < end; ++j) {
        const int c = ccol[j];
        const float v = cval[j];
        const float4 s = *reinterpret_cast<const float4*>(S + (size_t)c * 64 + f4 * 4);
        acc.x = fmaf(v, s.x, acc.x);
        acc.y = fmaf(v, s.y, acc.y);
        acc.z = fmaf(v, s.z, acc.z);
        acc.w = fmaf(v, s.w, acc.w);
    }
    *reinterpret_cast<float4*>(out + (size_t)node * 64 + f4 * 4) = acc;
}

extern "C" void kernel_launch(void* const* d_in, const int* in_sizes, int n_in,
                              void* d_out, int out_size, void* d_ws, size_t ws_size,
                              hipStream_t stream) {
    const float* x    = (const float*)d_in[0];
    const int*   erow = (const int*)d_in[1];
    const int*   ecol = (const int*)d_in[2];
    const float* eval = (const float*)d_in[3];
    const float* W1   = (const float*)d_in[4];
    const float* b1   = (const float*)d_in[5];
    const float* W2   = (const float*)d_in[6];
    const float* b2   = (const float*)d_in[7];
    const float* W3   = (const float*)d_in[8];
    const float* b3   = (const float*)d_in[9];
    float* out = (float*)d_out;

    const size_t nf = (size_t)N_NODES * 128;
    unsigned short* Xb  = (unsigned short*)d_ws;
    unsigned short* Ab  = Xb + nf;
    unsigned short* Wt1 = Ab + nf;
    unsigned short* Wt2 = Wt1 + 128 * 128;
    unsigned short* Wt3 = Wt2 + 128 * 128;
    int*   deg    = (int*)(Wt3 + 64 * 128);
    int*   rptr   = deg + N_NODES;
    int*   cursor = rptr + (N_NODES + 1);
    int*   ccol   = cursor + N_NODES;
    float* cval   = (float*)(ccol + N_EDGES);
    int*   slocal = (int*)(cval + N_EDGES);   // N_NODES tile-local prefixes
    int*   stsum  = slocal + N_NODES;         // tile totals
    float* Af     = (float*)Ab;               // layer-3 fp32 support [N,64]

    const int blk = 256;
    const int gemm_grid = (N_NODES + 63) / 64;
    const int agg_grid = (N_NODES * 16 + blk - 1) / blk;
    const int ntiles = (N_NODES + SCAN_TILE - 1) / SCAN_TILE;

    // ---- precompute: conversions + CSR
    {
        long long n4 = nf / 4;
        convert_f32_bf16<<<(int)((n4 + blk - 1) / blk), blk, 0, stream>>>(x, Xb, n4);
    }
    convert_w_t<128, 128><<<(128 * 128 + blk - 1) / blk, blk, 0, stream>>>(W1, Wt1);
    convert_w_t<128, 128><<<(128 * 128 + blk - 1) / blk, blk, 0, stream>>>(W2, Wt2);
    convert_w_t<128, 64><<<(128 * 64 + blk - 1) / blk, blk, 0, stream>>>(W3, Wt3);
    zero_ints<<<(N_NODES + blk - 1) / blk, blk, 0, stream>>>(deg, N_NODES);
    degree_histogram<<<(N_EDGES + blk - 1) / blk, blk, 0, stream>>>(erow, deg);
    scan_tiles<<<ntiles, 256, 0, stream>>>(deg, slocal, stsum, N_NODES);
    scan_finalize<<<ntiles, 256, 0, stream>>>(slocal, stsum, ntiles, rptr, cursor,
                                              N_NODES);
    fill_csr<<<(N_EDGES + blk - 1) / blk, blk, 0, stream>>>(erow, ecol, eval,
                                                            cursor, ccol, cval);

    // ---- Layer 1
    gemm_mfma<128, true><<<gemm_grid, 256, 0, stream>>>(Xb, Wt1, Ab, N_NODES);
    aggregate_bf16<<<agg_grid, blk, 0, stream>>>(Ab, rptr, ccol, cval, b1, Xb, N_NODES);

    // ---- Layer 2
    gemm_mfma<128, true><<<gemm_grid, 256, 0, stream>>>(Xb, Wt2, Ab, N_NODES);
    aggregate_bf16<<<agg_grid, blk, 0, stream>>>(Ab, rptr, ccol, cval, b2, Xb, N_NODES);

    // ---- Layer 3 (fp32 support + fp32 aggregation into d_out)
    gemm_mfma<64, false><<<gemm_grid, 256, 0, stream>>>(Xb, Wt3, Af, N_NODES);
    aggregate_f32_64<<<agg_grid, blk, 0, stream>>>(Af, rptr, ccol, cval, b3, out, N_NODES);
}

// Round 5
// 316.238 us; speedup vs baseline: 11.7650x; 1.1430x over previous
//
#include <hip/hip_runtime.h>

#define N_NODES 50000
#define N_EDGES 800000
#define SCAN_TILE 2048  // 256 threads x 8 elems

typedef __attribute__((ext_vector_type(4))) float f32x4;
typedef __attribute__((ext_vector_type(8))) short bf16x8;

__device__ inline unsigned short f32_to_bf16(float f) {
    unsigned int u = __builtin_bit_cast(unsigned int, f);
    u += 0x7FFF + ((u >> 16) & 1);  // RNE
    return (unsigned short)(u >> 16);
}
__device__ inline float bf16_to_f32(unsigned short h) {
    unsigned int u = ((unsigned int)h) << 16;
    return __builtin_bit_cast(float, u);
}

// ---------------------------------------------------------------------------
// fp32 -> bf16 elementwise (float4 in, 4x bf16 out)
// ---------------------------------------------------------------------------
__global__ void convert_f32_bf16(const float* __restrict__ in,
                                 unsigned short* __restrict__ out, long long n4) {
    long long i = (long long)blockIdx.x * blockDim.x + threadIdx.x;
    if (i >= n4) return;
    float4 v = reinterpret_cast<const float4*>(in)[i];
    ushort4 o;
    o.x = f32_to_bf16(v.x); o.y = f32_to_bf16(v.y);
    o.z = f32_to_bf16(v.z); o.w = f32_to_bf16(v.w);
    reinterpret_cast<ushort4*>(out)[i] = o;
}

// W[K][M] fp32 -> Wt[M][K] bf16 (grid-parallel)
template <int K, int M>
__global__ void convert_w_t(const float* __restrict__ W,
                            unsigned short* __restrict__ Wt) {
    int idx = blockIdx.x * blockDim.x + threadIdx.x;
    if (idx >= K * M) return;
    int k = idx / M, m = idx % M;
    Wt[m * K + k] = f32_to_bf16(W[idx]);
}

// ---------------------------------------------------------------------------
// CSR build: zero -> histogram -> two-kernel multi-block scan -> slot fill
// ---------------------------------------------------------------------------
__global__ void zero_ints(int* __restrict__ p, int n) {
    int i = blockIdx.x * blockDim.x + threadIdx.x;
    if (i < n) p[i] = 0;
}

__global__ void degree_histogram(const int* __restrict__ erow, int* __restrict__ deg) {
    int e = blockIdx.x * blockDim.x + threadIdx.x;
    if (e < N_EDGES) atomicAdd(&deg[erow[e]], 1);
}

__global__ void scan_tiles(const int* __restrict__ deg, int* __restrict__ local,
                           int* __restrict__ tsum, int n) {
    __shared__ int sums[256];
    const int t = threadIdx.x;
    const int base = blockIdx.x * SCAN_TILE + t * 8;
    int v[8];
    int s = 0;
#pragma unroll
    for (int i = 0; i < 8; ++i) {
        v[i] = (base + i < n) ? deg[base + i] : 0;
        s += v[i];
    }
    sums[t] = s;
    __syncthreads();
    for (int off = 1; off < 256; off <<= 1) {
        int x = (t >= off) ? sums[t - off] : 0;
        __syncthreads();
        sums[t] += x;
        __syncthreads();
    }
    int run = sums[t] - s;
#pragma unroll
    for (int i = 0; i < 8; ++i) {
        if (base + i < n) local[base + i] = run;
        run += v[i];
    }
    if (t == 255) tsum[blockIdx.x] = run;
}

__global__ void scan_finalize(const int* __restrict__ local,
                              const int* __restrict__ tsum, int ntiles,
                              int* __restrict__ rptr, int* __restrict__ cursor,
                              int n) {
    __shared__ int off_s;
    const int b = blockIdx.x;
    if (threadIdx.x == 0) {
        int s = 0;
        for (int i = 0; i < b; ++i) s += tsum[i];
        off_s = s;
        if (b == 0) {
            int tot = 0;
            for (int i = 0; i < ntiles; ++i) tot += tsum[i];
            rptr[n] = tot;
        }
    }
    __syncthreads();
    const int off = off_s;
    const int base = b * SCAN_TILE + threadIdx.x * 8;
#pragma unroll
    for (int i = 0; i < 8; ++i) {
        int idx = base + i;
        if (idx < n) {
            int v = local[idx] + off;
            rptr[idx] = v;
            cursor[idx] = v;
        }
    }
}

// Packed (col, val-as-int) single 8B scattered store per edge.
__global__ void fill_csr(const int* __restrict__ erow, const int* __restrict__ ecol,
                         const float* __restrict__ eval, int* __restrict__ cursor,
                         int2* __restrict__ cpack) {
    int e = blockIdx.x * blockDim.x + threadIdx.x;
    if (e >= N_EDGES) return;
    int slot = atomicAdd(&cursor[erow[e]], 1);
    int2 p;
    p.x = ecol[e];
    p.y = __float_as_int(eval[e]);
    cpack[slot] = p;
}

// ---------------------------------------------------------------------------
// MFMA GEMM: Y[N,NOUT] = Xb[N,128](bf16) @ W (staged transposed, bf16)
// 64 rows/block, 4 waves. Fragment layouts [measured m89/m91/m120].
// ---------------------------------------------------------------------------
template <int NOUT, bool OUT_BF16>
__global__ __launch_bounds__(256) void gemm_mfma(
    const unsigned short* __restrict__ Xb, const unsigned short* __restrict__ Wt,
    void* __restrict__ Yv, int N) {
    constexpr int K = 128;
    constexpr int KP = K + 8;
    constexpr int NT = NOUT / 16;
    __shared__ unsigned short Xs[64 * KP];
    __shared__ unsigned short Ws[NOUT * KP];

    const int tid = threadIdx.x;
    const int block_row = blockIdx.x * 64;

    for (int idx = tid; idx < 64 * 16; idx += 256) {
        int r = idx >> 4, ch = idx & 15;
        int gr = block_row + r;
        if (gr >= N) gr = N - 1;
        uint4 v = *reinterpret_cast<const uint4*>(Xb + (size_t)gr * K + ch * 8);
        *reinterpret_cast<uint4*>(Xs + r * KP + ch * 8) = v;
    }
    for (int idx = tid; idx < NOUT * 16; idx += 256) {
        int r = idx >> 4, ch = idx & 15;
        uint4 v = *reinterpret_cast<const uint4*>(Wt + r * K + ch * 8);
        *reinterpret_cast<uint4*>(Ws + r * KP + ch * 8) = v;
    }
    __syncthreads();

    const int wave = tid >> 6;
    const int lane = tid & 63;
    const int m = lane & 15;
    const int quad = lane >> 4;
    const int rowbase = wave * 16;

    f32x4 acc[NT];
#pragma unroll
    for (int t = 0; t < NT; ++t) acc[t] = (f32x4){0.f, 0.f, 0.f, 0.f};

#pragma unroll
    for (int kt = 0; kt < 4; ++kt) {
        bf16x8 a = *reinterpret_cast<const bf16x8*>(Xs + (rowbase + m) * KP + kt * 32 + quad * 8);
#pragma unroll
        for (int t = 0; t < NT; ++t) {
            bf16x8 b = *reinterpret_cast<const bf16x8*>(Ws + (t * 16 + m) * KP + kt * 32 + quad * 8);
            acc[t] = __builtin_amdgcn_mfma_f32_16x16x32_bf16(a, b, acc[t], 0, 0, 0);
        }
    }

#pragma unroll
    for (int t = 0; t < NT; ++t) {
#pragma unroll
        for (int r = 0; r < 4; ++r) {
            int grow = block_row + rowbase + quad * 4 + r;
            if (grow < N) {
                if (OUT_BF16)
                    reinterpret_cast<unsigned short*>(Yv)[(size_t)grow * NOUT + t * 16 + m] =
                        f32_to_bf16(acc[t][r]);
                else
                    reinterpret_cast<float*>(Yv)[(size_t)grow * NOUT + t * 16 + m] = acc[t][r];
            }
        }
    }
}

// ---------------------------------------------------------------------------
// CSR aggregation, bf16 source [N,128], fused bias+ReLU, bf16 out.
// 16 lanes/node, 8 features/lane; j-loop unrolled x2 for MLP.
// ---------------------------------------------------------------------------
__global__ void aggregate_bf16(const unsigned short* __restrict__ S,
                               const int* __restrict__ rptr,
                               const int2* __restrict__ cpack,
                               const float* __restrict__ bias,
                               unsigned short* __restrict__ outb, int N) {
    const int node = blockIdx.x * (blockDim.x / 16) + threadIdx.x / 16;
    const int f8 = threadIdx.x & 15;
    if (node >= N) return;
    const int beg = rptr[node];
    const int end = rptr[node + 1];
    float acc[8];
#pragma unroll
    for (int i = 0; i < 8; ++i) acc[i] = bias[f8 * 8 + i];
    int j = beg;
    for (; j + 1 < end; j += 2) {
        int2 p0 = cpack[j];
        int2 p1 = cpack[j + 1];
        uint4 s0 = *reinterpret_cast<const uint4*>(S + (size_t)p0.x * 128 + f8 * 8);
        uint4 s1 = *reinterpret_cast<const uint4*>(S + (size_t)p1.x * 128 + f8 * 8);
        const float v0 = __int_as_float(p0.y);
        const float v1 = __int_as_float(p1.y);
        const unsigned short* sp0 = reinterpret_cast<const unsigned short*>(&s0);
        const unsigned short* sp1 = reinterpret_cast<const unsigned short*>(&s1);
#pragma unroll
        for (int i = 0; i < 8; ++i) acc[i] = fmaf(v0, bf16_to_f32(sp0[i]), acc[i]);
#pragma unroll
        for (int i = 0; i < 8; ++i) acc[i] = fmaf(v1, bf16_to_f32(sp1[i]), acc[i]);
    }
    if (j < end) {
        int2 p = cpack[j];
        uint4 s = *reinterpret_cast<const uint4*>(S + (size_t)p.x * 128 + f8 * 8);
        const float v = __int_as_float(p.y);
        const unsigned short* sp = reinterpret_cast<const unsigned short*>(&s);
#pragma unroll
        for (int i = 0; i < 8; ++i) acc[i] = fmaf(v, bf16_to_f32(sp[i]), acc[i]);
    }
    unsigned short o[8];
#pragma unroll
    for (int i = 0; i < 8; ++i) o[i] = f32_to_bf16(fmaxf(acc[i], 0.0f));
    *reinterpret_cast<uint4*>(outb + (size_t)node * 128 + f8 * 8) =
        *reinterpret_cast<uint4*>(o);
}

// ---------------------------------------------------------------------------
// Layer-3 aggregation: bf16 source [N,64], + bias, no activation, fp32 out.
// 16 lanes/node, 4 features/lane (uint2 = 4 bf16); j-loop unrolled x2.
// ---------------------------------------------------------------------------
__global__ void aggregate_bf16_64(const unsigned short* __restrict__ S,
                                  const int* __restrict__ rptr,
                                  const int2* __restrict__ cpack,
                                  const float* __restrict__ bias,
                                  float* __restrict__ out, int N) {
    const int node = blockIdx.x * (blockDim.x / 16) + threadIdx.x / 16;
    const int f4 = threadIdx.x & 15;
    if (node >= N) return;
    const int beg = rptr[node];
    const int end = rptr[node + 1];
    float acc[4];
#pragma unroll
    for (int i = 0; i < 4; ++i) acc[i] = bias[f4 * 4 + i];
    int j = beg;
    for (; j + 1 < end; j += 2) {
        int2 p0 = cpack[j];
        int2 p1 = cpack[j + 1];
        uint2 s0 = *reinterpret_cast<const uint2*>(S + (size_t)p0.x * 64 + f4 * 4);
        uint2 s1 = *reinterpret_cast<const uint2*>(S + (size_t)p1.x * 64 + f4 * 4);
        const float v0 = __int_as_float(p0.y);
        const float v1 = __int_as_float(p1.y);
        const unsigned short* sp0 = reinterpret_cast<const unsigned short*>(&s0);
        const unsigned short* sp1 = reinterpret_cast<const unsigned short*>(&s1);
#pragma unroll
        for (int i = 0; i < 4; ++i) acc[i] = fmaf(v0, bf16_to_f32(sp0[i]), acc[i]);
#pragma unroll
        for (int i = 0; i < 4; ++i) acc[i] = fmaf(v1, bf16_to_f32(sp1[i]), acc[i]);
    }
    if (j < end) {
        int2 p = cpack[j];
        uint2 s = *reinterpret_cast<const uint2*>(S + (size_t)p.x * 64 + f4 * 4);
        const float v = __int_as_float(p.y);
        const unsigned short* sp = reinterpret_cast<const unsigned short*>(&s);
#pragma unroll
        for (int i = 0; i < 4; ++i) acc[i] = fmaf(v, bf16_to_f32(sp[i]), acc[i]);
    }
    float4 o = {acc[0], acc[1], acc[2], acc[3]};
    *reinterpret_cast<float4*>(out + (size_t)node * 64 + f4 * 4) = o;
}

extern "C" void kernel_launch(void* const* d_in, const int* in_sizes, int n_in,
                              void* d_out, int out_size, void* d_ws, size_t ws_size,
                              hipStream_t stream) {
    const float* x    = (const float*)d_in[0];
    const int*   erow = (const int*)d_in[1];
    const int*   ecol = (const int*)d_in[2];
    const float* eval = (const float*)d_in[3];
    const float* W1   = (const float*)d_in[4];
    const float* b1   = (const float*)d_in[5];
    const float* W2   = (const float*)d_in[6];
    const float* b2   = (const float*)d_in[7];
    const float* W3   = (const float*)d_in[8];
    const float* b3   = (const float*)d_in[9];
    float* out = (float*)d_out;

    const size_t nf = (size_t)N_NODES * 128;
    unsigned short* Xb  = (unsigned short*)d_ws;
    unsigned short* Ab  = Xb + nf;
    unsigned short* Wt1 = Ab + nf;
    unsigned short* Wt2 = Wt1 + 128 * 128;
    unsigned short* Wt3 = Wt2 + 128 * 128;
    int*   deg    = (int*)(Wt3 + 64 * 128);
    int*   rptr   = deg + N_NODES;
    int*   cursor = rptr + (N_NODES + 1);
    // align cpack to 16B
    char*  pbase  = (char*)(cursor + N_NODES);
    pbase = (char*)(((size_t)pbase + 15) & ~(size_t)15);
    int2*  cpack  = (int2*)pbase;
    int*   slocal = (int*)(cpack + N_EDGES);
    int*   stsum  = slocal + N_NODES;

    const int blk = 256;
    const int gemm_grid = (N_NODES + 63) / 64;
    const int agg_grid = (N_NODES * 16 + blk - 1) / blk;
    const int ntiles = (N_NODES + SCAN_TILE - 1) / SCAN_TILE;

    // ---- precompute: conversions + CSR
    {
        long long n4 = nf / 4;
        convert_f32_bf16<<<(int)((n4 + blk - 1) / blk), blk, 0, stream>>>(x, Xb, n4);
    }
    convert_w_t<128, 128><<<(128 * 128 + blk - 1) / blk, blk, 0, stream>>>(W1, Wt1);
    convert_w_t<128, 128><<<(128 * 128 + blk - 1) / blk, blk, 0, stream>>>(W2, Wt2);
    convert_w_t<128, 64><<<(128 * 64 + blk - 1) / blk, blk, 0, stream>>>(W3, Wt3);
    zero_ints<<<(N_NODES + blk - 1) / blk, blk, 0, stream>>>(deg, N_NODES);
    degree_histogram<<<(N_EDGES + blk - 1) / blk, blk, 0, stream>>>(erow, deg);
    scan_tiles<<<ntiles, 256, 0, stream>>>(deg, slocal, stsum, N_NODES);
    scan_finalize<<<ntiles, 256, 0, stream>>>(slocal, stsum, ntiles, rptr, cursor,
                                              N_NODES);
    fill_csr<<<(N_EDGES + blk - 1) / blk, blk, 0, stream>>>(erow, ecol, eval,
                                                            cursor, cpack);

    // ---- Layer 1
    gemm_mfma<128, true><<<gemm_grid, 256, 0, stream>>>(Xb, Wt1, Ab, N_NODES);
    aggregate_bf16<<<agg_grid, blk, 0, stream>>>(Ab, rptr, cpack, b1, Xb, N_NODES);

    // ---- Layer 2
    gemm_mfma<128, true><<<gemm_grid, 256, 0, stream>>>(Xb, Wt2, Ab, N_NODES);
    aggregate_bf16<<<agg_grid, blk, 0, stream>>>(Ab, rptr, cpack, b2, Xb, N_NODES);

    // ---- Layer 3 (bf16 support, fp32 accumulate + fp32 out)
    gemm_mfma<64, true><<<gemm_grid, 256, 0, stream>>>(Xb, Wt3, Ab, N_NODES);
    aggregate_bf16_64<<<agg_grid, blk, 0, stream>>>(Ab, rptr, cpack, b3, out, N_NODES);
}

// Round 6
// 310.485 us; speedup vs baseline: 11.9830x; 1.0185x over previous
//
#include <hip/hip_runtime.h>

#define N_NODES 50000
#define N_EDGES 800000
#define SCAN_TILE 2048  // 256 threads x 8 elems

static_assert(N_NODES < 65536, "col must fit in 16 bits for packed CSR");

typedef __attribute__((ext_vector_type(4))) float f32x4;
typedef __attribute__((ext_vector_type(8))) short bf16x8;

__device__ inline unsigned short f32_to_bf16(float f) {
    unsigned int u = __builtin_bit_cast(unsigned int, f);
    u += 0x7FFF + ((u >> 16) & 1);  // RNE
    return (unsigned short)(u >> 16);
}
__device__ inline float bf16_to_f32(unsigned short h) {
    unsigned int u = ((unsigned int)h) << 16;
    return __builtin_bit_cast(float, u);
}

// ---------------------------------------------------------------------------
// fp32 -> bf16 elementwise (float4 in, 4x bf16 out)
// ---------------------------------------------------------------------------
__global__ void convert_f32_bf16(const float* __restrict__ in,
                                 unsigned short* __restrict__ out, long long n4) {
    long long i = (long long)blockIdx.x * blockDim.x + threadIdx.x;
    if (i >= n4) return;
    float4 v = reinterpret_cast<const float4*>(in)[i];
    ushort4 o;
    o.x = f32_to_bf16(v.x); o.y = f32_to_bf16(v.y);
    o.z = f32_to_bf16(v.z); o.w = f32_to_bf16(v.w);
    reinterpret_cast<ushort4*>(out)[i] = o;
}

// W[K][M] fp32 -> Wt[M][K] bf16 (grid-parallel)
template <int K, int M>
__global__ void convert_w_t(const float* __restrict__ W,
                            unsigned short* __restrict__ Wt) {
    int idx = blockIdx.x * blockDim.x + threadIdx.x;
    if (idx >= K * M) return;
    int k = idx / M, m = idx % M;
    Wt[m * K + k] = f32_to_bf16(W[idx]);
}

// ---------------------------------------------------------------------------
// CSR build: zero -> histogram -> two-kernel multi-block scan -> slot fill
// ---------------------------------------------------------------------------
__global__ void zero_ints(int* __restrict__ p, int n) {
    int i = blockIdx.x * blockDim.x + threadIdx.x;
    if (i < n) p[i] = 0;
}

__global__ void degree_histogram(const int* __restrict__ erow, int* __restrict__ deg) {
    int e = blockIdx.x * blockDim.x + threadIdx.x;
    if (e < N_EDGES) atomicAdd(&deg[erow[e]], 1);
}

__global__ void scan_tiles(const int* __restrict__ deg, int* __restrict__ local,
                           int* __restrict__ tsum, int n) {
    __shared__ int sums[256];
    const int t = threadIdx.x;
    const int base = blockIdx.x * SCAN_TILE + t * 8;
    int v[8];
    int s = 0;
#pragma unroll
    for (int i = 0; i < 8; ++i) {
        v[i] = (base + i < n) ? deg[base + i] : 0;
        s += v[i];
    }
    sums[t] = s;
    __syncthreads();
    for (int off = 1; off < 256; off <<= 1) {
        int x = (t >= off) ? sums[t - off] : 0;
        __syncthreads();
        sums[t] += x;
        __syncthreads();
    }
    int run = sums[t] - s;
#pragma unroll
    for (int i = 0; i < 8; ++i) {
        if (base + i < n) local[base + i] = run;
        run += v[i];
    }
    if (t == 255) tsum[blockIdx.x] = run;
}

__global__ void scan_finalize(const int* __restrict__ local,
                              const int* __restrict__ tsum, int ntiles,
                              int* __restrict__ rptr, int* __restrict__ cursor,
                              int n) {
    __shared__ int off_s;
    const int b = blockIdx.x;
    if (threadIdx.x == 0) {
        int s = 0;
        for (int i = 0; i < b; ++i) s += tsum[i];
        off_s = s;
        if (b == 0) {
            int tot = 0;
            for (int i = 0; i < ntiles; ++i) tot += tsum[i];
            rptr[n] = tot;
        }
    }
    __syncthreads();
    const int off = off_s;
    const int base = b * SCAN_TILE + threadIdx.x * 8;
#pragma unroll
    for (int i = 0; i < 8; ++i) {
        int idx = base + i;
        if (idx < n) {
            int v = local[idx] + off;
            rptr[idx] = v;
            cursor[idx] = v;
        }
    }
}

// Packed 4B per edge: low 16 bits = col, high 16 bits = val as bf16.
__global__ void fill_csr(const int* __restrict__ erow, const int* __restrict__ ecol,
                         const float* __restrict__ eval, int* __restrict__ cursor,
                         unsigned int* __restrict__ cpack) {
    int e = blockIdx.x * blockDim.x + threadIdx.x;
    if (e >= N_EDGES) return;
    int slot = atomicAdd(&cursor[erow[e]], 1);
    unsigned int p = (unsigned int)(ecol[e] & 0xFFFF) |
                     ((unsigned int)f32_to_bf16(eval[e]) << 16);
    cpack[slot] = p;
}

// ---------------------------------------------------------------------------
// MFMA GEMM (persistent-W, grid-stride over 64-row tiles):
// Y[N,NOUT] = Xb[N,128](bf16) @ W (staged transposed, bf16)
// 256 blocks x 4 waves; Wt staged to LDS once per block, reused for ~3 tiles.
// Fragment layouts [measured m89/m91/m120].
// ---------------------------------------------------------------------------
template <int NOUT, bool OUT_BF16>
__global__ __launch_bounds__(256) void gemm_mfma(
    const unsigned short* __restrict__ Xb, const unsigned short* __restrict__ Wt,
    void* __restrict__ Yv, int N, int ntiles) {
    constexpr int K = 128;
    constexpr int KP = K + 8;
    constexpr int NT = NOUT / 16;
    __shared__ unsigned short Xs[64 * KP];
    __shared__ unsigned short Ws[NOUT * KP];

    const int tid = threadIdx.x;
    const int wave = tid >> 6;
    const int lane = tid & 63;
    const int m = lane & 15;
    const int quad = lane >> 4;
    const int rowbase = wave * 16;

    // stage Wt once per block
    for (int idx = tid; idx < NOUT * 16; idx += 256) {
        int r = idx >> 4, ch = idx & 15;
        uint4 v = *reinterpret_cast<const uint4*>(Wt + r * K + ch * 8);
        *reinterpret_cast<uint4*>(Ws + r * KP + ch * 8) = v;
    }

    for (int tile = blockIdx.x; tile < ntiles; tile += gridDim.x) {
        const int block_row = tile * 64;
        // stage X tile (prev iteration's reads are fenced by the tail barrier)
        for (int idx = tid; idx < 64 * 16; idx += 256) {
            int r = idx >> 4, ch = idx & 15;
            int gr = block_row + r;
            if (gr >= N) gr = N - 1;
            uint4 v = *reinterpret_cast<const uint4*>(Xb + (size_t)gr * K + ch * 8);
            *reinterpret_cast<uint4*>(Xs + r * KP + ch * 8) = v;
        }
        __syncthreads();

        f32x4 acc[NT];
#pragma unroll
        for (int t = 0; t < NT; ++t) acc[t] = (f32x4){0.f, 0.f, 0.f, 0.f};

#pragma unroll
        for (int kt = 0; kt < 4; ++kt) {
            bf16x8 a = *reinterpret_cast<const bf16x8*>(
                Xs + (rowbase + m) * KP + kt * 32 + quad * 8);
#pragma unroll
            for (int t = 0; t < NT; ++t) {
                bf16x8 b = *reinterpret_cast<const bf16x8*>(
                    Ws + (t * 16 + m) * KP + kt * 32 + quad * 8);
                acc[t] = __builtin_amdgcn_mfma_f32_16x16x32_bf16(a, b, acc[t], 0, 0, 0);
            }
        }
        __syncthreads();  // all Xs reads done before next stage

#pragma unroll
        for (int t = 0; t < NT; ++t) {
#pragma unroll
            for (int r = 0; r < 4; ++r) {
                int grow = block_row + rowbase + quad * 4 + r;
                if (grow < N) {
                    if (OUT_BF16)
                        reinterpret_cast<unsigned short*>(Yv)[(size_t)grow * NOUT + t * 16 + m] =
                            f32_to_bf16(acc[t][r]);
                    else
                        reinterpret_cast<float*>(Yv)[(size_t)grow * NOUT + t * 16 + m] = acc[t][r];
                }
            }
        }
    }
}

// ---------------------------------------------------------------------------
// CSR aggregation, bf16 source [N,128], fused bias+ReLU, bf16 out.
// 16 lanes/node, 8 features/lane; j-loop unrolled x4 for MLP.
// ---------------------------------------------------------------------------
__global__ void aggregate_bf16(const unsigned short* __restrict__ S,
                               const int* __restrict__ rptr,
                               const unsigned int* __restrict__ cpack,
                               const float* __restrict__ bias,
                               unsigned short* __restrict__ outb, int N) {
    const int node = blockIdx.x * (blockDim.x / 16) + threadIdx.x / 16;
    const int f8 = threadIdx.x & 15;
    if (node >= N) return;
    const int beg = rptr[node];
    const int end = rptr[node + 1];
    float acc[8];
#pragma unroll
    for (int i = 0; i < 8; ++i) acc[i] = bias[f8 * 8 + i];
    int j = beg;
    for (; j + 3 < end; j += 4) {
        unsigned int p0 = cpack[j], p1 = cpack[j + 1];
        unsigned int p2 = cpack[j + 2], p3 = cpack[j + 3];
        uint4 s0 = *reinterpret_cast<const uint4*>(S + (size_t)(p0 & 0xFFFF) * 128 + f8 * 8);
        uint4 s1 = *reinterpret_cast<const uint4*>(S + (size_t)(p1 & 0xFFFF) * 128 + f8 * 8);
        uint4 s2 = *reinterpret_cast<const uint4*>(S + (size_t)(p2 & 0xFFFF) * 128 + f8 * 8);
        uint4 s3 = *reinterpret_cast<const uint4*>(S + (size_t)(p3 & 0xFFFF) * 128 + f8 * 8);
        const float v0 = bf16_to_f32((unsigned short)(p0 >> 16));
        const float v1 = bf16_to_f32((unsigned short)(p1 >> 16));
        const float v2 = bf16_to_f32((unsigned short)(p2 >> 16));
        const float v3 = bf16_to_f32((unsigned short)(p3 >> 16));
        const unsigned short* sp0 = reinterpret_cast<const unsigned short*>(&s0);
        const unsigned short* sp1 = reinterpret_cast<const unsigned short*>(&s1);
        const unsigned short* sp2 = reinterpret_cast<const unsigned short*>(&s2);
        const unsigned short* sp3 = reinterpret_cast<const unsigned short*>(&s3);
#pragma unroll
        for (int i = 0; i < 8; ++i) acc[i] = fmaf(v0, bf16_to_f32(sp0[i]), acc[i]);
#pragma unroll
        for (int i = 0; i < 8; ++i) acc[i] = fmaf(v1, bf16_to_f32(sp1[i]), acc[i]);
#pragma unroll
        for (int i = 0; i < 8; ++i) acc[i] = fmaf(v2, bf16_to_f32(sp2[i]), acc[i]);
#pragma unroll
        for (int i = 0; i < 8; ++i) acc[i] = fmaf(v3, bf16_to_f32(sp3[i]), acc[i]);
    }
    for (; j < end; ++j) {
        unsigned int p = cpack[j];
        uint4 s = *reinterpret_cast<const uint4*>(S + (size_t)(p & 0xFFFF) * 128 + f8 * 8);
        const float v = bf16_to_f32((unsigned short)(p >> 16));
        const unsigned short* sp = reinterpret_cast<const unsigned short*>(&s);
#pragma unroll
        for (int i = 0; i < 8; ++i) acc[i] = fmaf(v, bf16_to_f32(sp[i]), acc[i]);
    }
    unsigned short o[8];
#pragma unroll
    for (int i = 0; i < 8; ++i) o[i] = f32_to_bf16(fmaxf(acc[i], 0.0f));
    *reinterpret_cast<uint4*>(outb + (size_t)node * 128 + f8 * 8) =
        *reinterpret_cast<uint4*>(o);
}

// ---------------------------------------------------------------------------
// Layer-3 aggregation: bf16 source [N,64], + bias, no activation, fp32 out.
// 16 lanes/node, 4 features/lane; j-loop unrolled x4.
// ---------------------------------------------------------------------------
__global__ void aggregate_bf16_64(const unsigned short* __restrict__ S,
                                  const int* __restrict__ rptr,
                                  const unsigned int* __restrict__ cpack,
                                  const float* __restrict__ bias,
                                  float* __restrict__ out, int N) {
    const int node = blockIdx.x * (blockDim.x / 16) + threadIdx.x / 16;
    const int f4 = threadIdx.x & 15;
    if (node >= N) return;
    const int beg = rptr[node];
    const int end = rptr[node + 1];
    float acc[4];
#pragma unroll
    for (int i = 0; i < 4; ++i) acc[i] = bias[f4 * 4 + i];
    int j = beg;
    for (; j + 3 < end; j += 4) {
        unsigned int p0 = cpack[j], p1 = cpack[j + 1];
        unsigned int p2 = cpack[j + 2], p3 = cpack[j + 3];
        uint2 s0 = *reinterpret_cast<const uint2*>(S + (size_t)(p0 & 0xFFFF) * 64 + f4 * 4);
        uint2 s1 = *reinterpret_cast<const uint2*>(S + (size_t)(p1 & 0xFFFF) * 64 + f4 * 4);
        uint2 s2 = *reinterpret_cast<const uint2*>(S + (size_t)(p2 & 0xFFFF) * 64 + f4 * 4);
        uint2 s3 = *reinterpret_cast<const uint2*>(S + (size_t)(p3 & 0xFFFF) * 64 + f4 * 4);
        const float v0 = bf16_to_f32((unsigned short)(p0 >> 16));
        const float v1 = bf16_to_f32((unsigned short)(p1 >> 16));
        const float v2 = bf16_to_f32((unsigned short)(p2 >> 16));
        const float v3 = bf16_to_f32((unsigned short)(p3 >> 16));
        const unsigned short* sp0 = reinterpret_cast<const unsigned short*>(&s0);
        const unsigned short* sp1 = reinterpret_cast<const unsigned short*>(&s1);
        const unsigned short* sp2 = reinterpret_cast<const unsigned short*>(&s2);
        const unsigned short* sp3 = reinterpret_cast<const unsigned short*>(&s3);
#pragma unroll
        for (int i = 0; i < 4; ++i) acc[i] = fmaf(v0, bf16_to_f32(sp0[i]), acc[i]);
#pragma unroll
        for (int i = 0; i < 4; ++i) acc[i] = fmaf(v1, bf16_to_f32(sp1[i]), acc[i]);
#pragma unroll
        for (int i = 0; i < 4; ++i) acc[i] = fmaf(v2, bf16_to_f32(sp2[i]), acc[i]);
#pragma unroll
        for (int i = 0; i < 4; ++i) acc[i] = fmaf(v3, bf16_to_f32(sp3[i]), acc[i]);
    }
    for (; j < end; ++j) {
        unsigned int p = cpack[j];
        uint2 s = *reinterpret_cast<const uint2*>(S + (size_t)(p & 0xFFFF) * 64 + f4 * 4);
        const float v = bf16_to_f32((unsigned short)(p >> 16));
        const unsigned short* sp = reinterpret_cast<const unsigned short*>(&s);
#pragma unroll
        for (int i = 0; i < 4; ++i) acc[i] = fmaf(v, bf16_to_f32(sp[i]), acc[i]);
    }
    float4 o = {acc[0], acc[1], acc[2], acc[3]};
    *reinterpret_cast<float4*>(out + (size_t)node * 64 + f4 * 4) = o;
}

extern "C" void kernel_launch(void* const* d_in, const int* in_sizes, int n_in,
                              void* d_out, int out_size, void* d_ws, size_t ws_size,
                              hipStream_t stream) {
    const float* x    = (const float*)d_in[0];
    const int*   erow = (const int*)d_in[1];
    const int*   ecol = (const int*)d_in[2];
    const float* eval = (const float*)d_in[3];
    const float* W1   = (const float*)d_in[4];
    const float* b1   = (const float*)d_in[5];
    const float* W2   = (const float*)d_in[6];
    const float* b2   = (const float*)d_in[7];
    const float* W3   = (const float*)d_in[8];
    const float* b3   = (const float*)d_in[9];
    float* out = (float*)d_out;

    const size_t nf = (size_t)N_NODES * 128;
    unsigned short* Xb  = (unsigned short*)d_ws;
    unsigned short* Ab  = Xb + nf;
    unsigned short* Wt1 = Ab + nf;
    unsigned short* Wt2 = Wt1 + 128 * 128;
    unsigned short* Wt3 = Wt2 + 128 * 128;
    int*   deg    = (int*)(Wt3 + 64 * 128);
    int*   rptr   = deg + N_NODES;
    int*   cursor = rptr + (N_NODES + 1);
    unsigned int* cpack = (unsigned int*)(cursor + N_NODES);
    int*   slocal = (int*)(cpack + N_EDGES);
    int*   stsum  = slocal + N_NODES;

    const int blk = 256;
    const int ntiles_g = (N_NODES + 63) / 64;
    const int gemm_grid = 256;  // persistent blocks, grid-stride over tiles
    const int agg_grid = (N_NODES * 16 + blk - 1) / blk;
    const int ntiles = (N_NODES + SCAN_TILE - 1) / SCAN_TILE;

    // ---- precompute: conversions + CSR
    {
        long long n4 = nf / 4;
        convert_f32_bf16<<<(int)((n4 + blk - 1) / blk), blk, 0, stream>>>(x, Xb, n4);
    }
    convert_w_t<128, 128><<<(128 * 128 + blk - 1) / blk, blk, 0, stream>>>(W1, Wt1);
    convert_w_t<128, 128><<<(128 * 128 + blk - 1) / blk, blk, 0, stream>>>(W2, Wt2);
    convert_w_t<128, 64><<<(128 * 64 + blk - 1) / blk, blk, 0, stream>>>(W3, Wt3);
    zero_ints<<<(N_NODES + blk - 1) / blk, blk, 0, stream>>>(deg, N_NODES);
    degree_histogram<<<(N_EDGES + blk - 1) / blk, blk, 0, stream>>>(erow, deg);
    scan_tiles<<<ntiles, 256, 0, stream>>>(deg, slocal, stsum, N_NODES);
    scan_finalize<<<ntiles, 256, 0, stream>>>(slocal, stsum, ntiles, rptr, cursor,
                                              N_NODES);
    fill_csr<<<(N_EDGES + blk - 1) / blk, blk, 0, stream>>>(erow, ecol, eval,
                                                            cursor, cpack);

    // ---- Layer 1
    gemm_mfma<128, true><<<gemm_grid, 256, 0, stream>>>(Xb, Wt1, Ab, N_NODES, ntiles_g);
    aggregate_bf16<<<agg_grid, blk, 0, stream>>>(Ab, rptr, cpack, b1, Xb, N_NODES);

    // ---- Layer 2
    gemm_mfma<128, true><<<gemm_grid, 256, 0, stream>>>(Xb, Wt2, Ab, N_NODES, ntiles_g);
    aggregate_bf16<<<agg_grid, blk, 0, stream>>>(Ab, rptr, cpack, b2, Xb, N_NODES);

    // ---- Layer 3 (bf16 support, fp32 accumulate + fp32 out)
    gemm_mfma<64, true><<<gemm_grid, 256, 0, stream>>>(Xb, Wt3, Ab, N_NODES, ntiles_g);
    aggregate_bf16_64<<<agg_grid, blk, 0, stream>>>(Ab, rptr, cpack, b3, out, N_NODES);
}

// Round 7
// 276.373 us; speedup vs baseline: 13.4621x; 1.1234x over previous
//
#include <hip/hip_runtime.h>

#define N_NODES 50000
#define N_EDGES 800000
#define SCAN_TILE 2048  // 256 threads x 8 elems
#define CNT_STRIDE 16   // one counter per 64B line (kills false sharing)

static_assert(N_NODES < 65536, "col must fit in 16 bits for packed CSR");

typedef __attribute__((ext_vector_type(4))) float f32x4;
typedef __attribute__((ext_vector_type(8))) short bf16x8;

__device__ inline unsigned short f32_to_bf16(float f) {
    unsigned int u = __builtin_bit_cast(unsigned int, f);
    u += 0x7FFF + ((u >> 16) & 1);  // RNE
    return (unsigned short)(u >> 16);
}
__device__ inline float bf16_to_f32(unsigned short h) {
    unsigned int u = ((unsigned int)h) << 16;
    return __builtin_bit_cast(float, u);
}

// ---------------------------------------------------------------------------
// fp32 -> bf16 elementwise (float4 in, 4x bf16 out)
// ---------------------------------------------------------------------------
__global__ void convert_f32_bf16(const float* __restrict__ in,
                                 unsigned short* __restrict__ out, long long n4) {
    long long i = (long long)blockIdx.x * blockDim.x + threadIdx.x;
    if (i >= n4) return;
    float4 v = reinterpret_cast<const float4*>(in)[i];
    ushort4 o;
    o.x = f32_to_bf16(v.x); o.y = f32_to_bf16(v.y);
    o.z = f32_to_bf16(v.z); o.w = f32_to_bf16(v.w);
    reinterpret_cast<ushort4*>(out)[i] = o;
}

// W[K][M] fp32 -> Wt[M][K] bf16 (grid-parallel)
template <int K, int M>
__global__ void convert_w_t(const float* __restrict__ W,
                            unsigned short* __restrict__ Wt) {
    int idx = blockIdx.x * blockDim.x + threadIdx.x;
    if (idx >= K * M) return;
    int k = idx / M, m = idx % M;
    Wt[m * K + k] = f32_to_bf16(W[idx]);
}

// ---------------------------------------------------------------------------
// CSR build: zero padded counters -> rank histogram (ONE atomic pass, rank
// returned) -> multi-block scan -> atomic-free slot fill
// ---------------------------------------------------------------------------
__global__ void zero_ints(int* __restrict__ p, int n) {
    int i = blockIdx.x * blockDim.x + threadIdx.x;
    if (i < n) p[i] = 0;
}

// rank[e] = position of edge e within its row (order nondeterministic, unique)
__global__ void rank_histogram(const int* __restrict__ erow, int* __restrict__ cnt,
                               int* __restrict__ rank) {
    int e = blockIdx.x * blockDim.x + threadIdx.x;
    if (e < N_EDGES) rank[e] = atomicAdd(&cnt[(size_t)erow[e] * CNT_STRIDE], 1);
}

// Tile-local exclusive scan over the padded counters.
__global__ void scan_tiles(const int* __restrict__ cnt, int* __restrict__ local,
                           int* __restrict__ tsum, int n) {
    __shared__ int sums[256];
    const int t = threadIdx.x;
    const int base = blockIdx.x * SCAN_TILE + t * 8;
    int v[8];
    int s = 0;
#pragma unroll
    for (int i = 0; i < 8; ++i) {
        v[i] = (base + i < n) ? cnt[(size_t)(base + i) * CNT_STRIDE] : 0;
        s += v[i];
    }
    sums[t] = s;
    __syncthreads();
    for (int off = 1; off < 256; off <<= 1) {
        int x = (t >= off) ? sums[t - off] : 0;
        __syncthreads();
        sums[t] += x;
        __syncthreads();
    }
    int run = sums[t] - s;
#pragma unroll
    for (int i = 0; i < 8; ++i) {
        if (base + i < n) local[base + i] = run;
        run += v[i];
    }
    if (t == 255) tsum[blockIdx.x] = run;
}

__global__ void scan_finalize(const int* __restrict__ local,
                              const int* __restrict__ tsum, int ntiles,
                              int* __restrict__ rptr, int n) {
    __shared__ int off_s;
    const int b = blockIdx.x;
    if (threadIdx.x == 0) {
        int s = 0;
        for (int i = 0; i < b; ++i) s += tsum[i];
        off_s = s;
        if (b == 0) {
            int tot = 0;
            for (int i = 0; i < ntiles; ++i) tot += tsum[i];
            rptr[n] = tot;
        }
    }
    __syncthreads();
    const int off = off_s;
    const int base = b * SCAN_TILE + threadIdx.x * 8;
#pragma unroll
    for (int i = 0; i < 8; ++i) {
        int idx = base + i;
        if (idx < n) rptr[idx] = local[idx] + off;
    }
}

// Atomic-free fill: slot = rptr[row] + rank[e]; one 4B scattered store.
__global__ void fill_csr(const int* __restrict__ erow, const int* __restrict__ ecol,
                         const float* __restrict__ eval, const int* __restrict__ rptr,
                         const int* __restrict__ rank,
                         unsigned int* __restrict__ cpack) {
    int e = blockIdx.x * blockDim.x + threadIdx.x;
    if (e >= N_EDGES) return;
    int slot = rptr[erow[e]] + rank[e];
    unsigned int p = (unsigned int)(ecol[e] & 0xFFFF) |
                     ((unsigned int)f32_to_bf16(eval[e]) << 16);
    cpack[slot] = p;
}

// ---------------------------------------------------------------------------
// MFMA GEMM (persistent-W, grid-stride over 64-row tiles):
// Y[N,NOUT] = Xb[N,128](bf16) @ W (staged transposed, bf16)
// Fragment layouts [measured m89/m91/m120].
// ---------------------------------------------------------------------------
template <int NOUT, bool OUT_BF16>
__global__ __launch_bounds__(256) void gemm_mfma(
    const unsigned short* __restrict__ Xb, const unsigned short* __restrict__ Wt,
    void* __restrict__ Yv, int N, int ntiles) {
    constexpr int K = 128;
    constexpr int KP = K + 8;
    constexpr int NT = NOUT / 16;
    __shared__ unsigned short Xs[64 * KP];
    __shared__ unsigned short Ws[NOUT * KP];

    const int tid = threadIdx.x;
    const int wave = tid >> 6;
    const int lane = tid & 63;
    const int m = lane & 15;
    const int quad = lane >> 4;
    const int rowbase = wave * 16;

    for (int idx = tid; idx < NOUT * 16; idx += 256) {
        int r = idx >> 4, ch = idx & 15;
        uint4 v = *reinterpret_cast<const uint4*>(Wt + r * K + ch * 8);
        *reinterpret_cast<uint4*>(Ws + r * KP + ch * 8) = v;
    }

    for (int tile = blockIdx.x; tile < ntiles; tile += gridDim.x) {
        const int block_row = tile * 64;
        for (int idx = tid; idx < 64 * 16; idx += 256) {
            int r = idx >> 4, ch = idx & 15;
            int gr = block_row + r;
            if (gr >= N) gr = N - 1;
            uint4 v = *reinterpret_cast<const uint4*>(Xb + (size_t)gr * K + ch * 8);
            *reinterpret_cast<uint4*>(Xs + r * KP + ch * 8) = v;
        }
        __syncthreads();

        f32x4 acc[NT];
#pragma unroll
        for (int t = 0; t < NT; ++t) acc[t] = (f32x4){0.f, 0.f, 0.f, 0.f};

#pragma unroll
        for (int kt = 0; kt < 4; ++kt) {
            bf16x8 a = *reinterpret_cast<const bf16x8*>(
                Xs + (rowbase + m) * KP + kt * 32 + quad * 8);
#pragma unroll
            for (int t = 0; t < NT; ++t) {
                bf16x8 b = *reinterpret_cast<const bf16x8*>(
                    Ws + (t * 16 + m) * KP + kt * 32 + quad * 8);
                acc[t] = __builtin_amdgcn_mfma_f32_16x16x32_bf16(a, b, acc[t], 0, 0, 0);
            }
        }
        __syncthreads();

#pragma unroll
        for (int t = 0; t < NT; ++t) {
#pragma unroll
            for (int r = 0; r < 4; ++r) {
                int grow = block_row + rowbase + quad * 4 + r;
                if (grow < N) {
                    if (OUT_BF16)
                        reinterpret_cast<unsigned short*>(Yv)[(size_t)grow * NOUT + t * 16 + m] =
                            f32_to_bf16(acc[t][r]);
                    else
                        reinterpret_cast<float*>(Yv)[(size_t)grow * NOUT + t * 16 + m] = acc[t][r];
                }
            }
        }
    }
}

// ---------------------------------------------------------------------------
// CSR aggregation, bf16 source [N,128], fused bias+ReLU, bf16 out.
// 16 lanes/node, 8 features/lane; j-loop unrolled x4 for MLP.
// ---------------------------------------------------------------------------
__global__ void aggregate_bf16(const unsigned short* __restrict__ S,
                               const int* __restrict__ rptr,
                               const unsigned int* __restrict__ cpack,
                               const float* __restrict__ bias,
                               unsigned short* __restrict__ outb, int N) {
    const int node = blockIdx.x * (blockDim.x / 16) + threadIdx.x / 16;
    const int f8 = threadIdx.x & 15;
    if (node >= N) return;
    const int beg = rptr[node];
    const int end = rptr[node + 1];
    float acc[8];
#pragma unroll
    for (int i = 0; i < 8; ++i) acc[i] = bias[f8 * 8 + i];
    int j = beg;
    for (; j + 3 < end; j += 4) {
        unsigned int p0 = cpack[j], p1 = cpack[j + 1];
        unsigned int p2 = cpack[j + 2], p3 = cpack[j + 3];
        uint4 s0 = *reinterpret_cast<const uint4*>(S + (size_t)(p0 & 0xFFFF) * 128 + f8 * 8);
        uint4 s1 = *reinterpret_cast<const uint4*>(S + (size_t)(p1 & 0xFFFF) * 128 + f8 * 8);
        uint4 s2 = *reinterpret_cast<const uint4*>(S + (size_t)(p2 & 0xFFFF) * 128 + f8 * 8);
        uint4 s3 = *reinterpret_cast<const uint4*>(S + (size_t)(p3 & 0xFFFF) * 128 + f8 * 8);
        const float v0 = bf16_to_f32((unsigned short)(p0 >> 16));
        const float v1 = bf16_to_f32((unsigned short)(p1 >> 16));
        const float v2 = bf16_to_f32((unsigned short)(p2 >> 16));
        const float v3 = bf16_to_f32((unsigned short)(p3 >> 16));
        const unsigned short* sp0 = reinterpret_cast<const unsigned short*>(&s0);
        const unsigned short* sp1 = reinterpret_cast<const unsigned short*>(&s1);
        const unsigned short* sp2 = reinterpret_cast<const unsigned short*>(&s2);
        const unsigned short* sp3 = reinterpret_cast<const unsigned short*>(&s3);
#pragma unroll
        for (int i = 0; i < 8; ++i) acc[i] = fmaf(v0, bf16_to_f32(sp0[i]), acc[i]);
#pragma unroll
        for (int i = 0; i < 8; ++i) acc[i] = fmaf(v1, bf16_to_f32(sp1[i]), acc[i]);
#pragma unroll
        for (int i = 0; i < 8; ++i) acc[i] = fmaf(v2, bf16_to_f32(sp2[i]), acc[i]);
#pragma unroll
        for (int i = 0; i < 8; ++i) acc[i] = fmaf(v3, bf16_to_f32(sp3[i]), acc[i]);
    }
    for (; j < end; ++j) {
        unsigned int p = cpack[j];
        uint4 s = *reinterpret_cast<const uint4*>(S + (size_t)(p & 0xFFFF) * 128 + f8 * 8);
        const float v = bf16_to_f32((unsigned short)(p >> 16));
        const unsigned short* sp = reinterpret_cast<const unsigned short*>(&s);
#pragma unroll
        for (int i = 0; i < 8; ++i) acc[i] = fmaf(v, bf16_to_f32(sp[i]), acc[i]);
    }
    unsigned short o[8];
#pragma unroll
    for (int i = 0; i < 8; ++i) o[i] = f32_to_bf16(fmaxf(acc[i], 0.0f));
    *reinterpret_cast<uint4*>(outb + (size_t)node * 128 + f8 * 8) =
        *reinterpret_cast<uint4*>(o);
}

// ---------------------------------------------------------------------------
// Layer-3 aggregation: bf16 source [N,64], + bias, no activation, fp32 out.
// ---------------------------------------------------------------------------
__global__ void aggregate_bf16_64(const unsigned short* __restrict__ S,
                                  const int* __restrict__ rptr,
                                  const unsigned int* __restrict__ cpack,
                                  const float* __restrict__ bias,
                                  float* __restrict__ out, int N) {
    const int node = blockIdx.x * (blockDim.x / 16) + threadIdx.x / 16;
    const int f4 = threadIdx.x & 15;
    if (node >= N) return;
    const int beg = rptr[node];
    const int end = rptr[node + 1];
    float acc[4];
#pragma unroll
    for (int i = 0; i < 4; ++i) acc[i] = bias[f4 * 4 + i];
    int j = beg;
    for (; j + 3 < end; j += 4) {
        unsigned int p0 = cpack[j], p1 = cpack[j + 1];
        unsigned int p2 = cpack[j + 2], p3 = cpack[j + 3];
        uint2 s0 = *reinterpret_cast<const uint2*>(S + (size_t)(p0 & 0xFFFF) * 64 + f4 * 4);
        uint2 s1 = *reinterpret_cast<const uint2*>(S + (size_t)(p1 & 0xFFFF) * 64 + f4 * 4);
        uint2 s2 = *reinterpret_cast<const uint2*>(S + (size_t)(p2 & 0xFFFF) * 64 + f4 * 4);
        uint2 s3 = *reinterpret_cast<const uint2*>(S + (size_t)(p3 & 0xFFFF) * 64 + f4 * 4);
        const float v0 = bf16_to_f32((unsigned short)(p0 >> 16));
        const float v1 = bf16_to_f32((unsigned short)(p1 >> 16));
        const float v2 = bf16_to_f32((unsigned short)(p2 >> 16));
        const float v3 = bf16_to_f32((unsigned short)(p3 >> 16));
        const unsigned short* sp0 = reinterpret_cast<const unsigned short*>(&s0);
        const unsigned short* sp1 = reinterpret_cast<const unsigned short*>(&s1);
        const unsigned short* sp2 = reinterpret_cast<const unsigned short*>(&s2);
        const unsigned short* sp3 = reinterpret_cast<const unsigned short*>(&s3);
#pragma unroll
        for (int i = 0; i < 4; ++i) acc[i] = fmaf(v0, bf16_to_f32(sp0[i]), acc[i]);
#pragma unroll
        for (int i = 0; i < 4; ++i) acc[i] = fmaf(v1, bf16_to_f32(sp1[i]), acc[i]);
#pragma unroll
        for (int i = 0; i < 4; ++i) acc[i] = fmaf(v2, bf16_to_f32(sp2[i]), acc[i]);
#pragma unroll
        for (int i = 0; i < 4; ++i) acc[i] = fmaf(v3, bf16_to_f32(sp3[i]), acc[i]);
    }
    for (; j < end; ++j) {
        unsigned int p = cpack[j];
        uint2 s = *reinterpret_cast<const uint2*>(S + (size_t)(p & 0xFFFF) * 64 + f4 * 4);
        const float v = bf16_to_f32((unsigned short)(p >> 16));
        const unsigned short* sp = reinterpret_cast<const unsigned short*>(&s);
#pragma unroll
        for (int i = 0; i < 4; ++i) acc[i] = fmaf(v, bf16_to_f32(sp[i]), acc[i]);
    }
    float4 o = {acc[0], acc[1], acc[2], acc[3]};
    *reinterpret_cast<float4*>(out + (size_t)node * 64 + f4 * 4) = o;
}

extern "C" void kernel_launch(void* const* d_in, const int* in_sizes, int n_in,
                              void* d_out, int out_size, void* d_ws, size_t ws_size,
                              hipStream_t stream) {
    const float* x    = (const float*)d_in[0];
    const int*   erow = (const int*)d_in[1];
    const int*   ecol = (const int*)d_in[2];
    const float* eval = (const float*)d_in[3];
    const float* W1   = (const float*)d_in[4];
    const float* b1   = (const float*)d_in[5];
    const float* W2   = (const float*)d_in[6];
    const float* b2   = (const float*)d_in[7];
    const float* W3   = (const float*)d_in[8];
    const float* b3   = (const float*)d_in[9];
    float* out = (float*)d_out;

    const size_t nf = (size_t)N_NODES * 128;
    unsigned short* Xb  = (unsigned short*)d_ws;
    unsigned short* Ab  = Xb + nf;
    unsigned short* Wt1 = Ab + nf;
    unsigned short* Wt2 = Wt1 + 128 * 128;
    unsigned short* Wt3 = Wt2 + 128 * 128;
    int*   cnt    = (int*)(Wt3 + 64 * 128);          // N_NODES * CNT_STRIDE
    int*   rank   = cnt + (size_t)N_NODES * CNT_STRIDE;  // N_EDGES
    int*   rptr   = rank + N_EDGES;                  // N_NODES + 1
    unsigned int* cpack = (unsigned int*)(rptr + N_NODES + 1);  // N_EDGES
    int*   slocal = (int*)(cpack + N_EDGES);         // N_NODES
    int*   stsum  = slocal + N_NODES;                // tiles

    const int blk = 256;
    const int ntiles_g = (N_NODES + 63) / 64;
    const int gemm_grid = 256;
    const int agg_grid = (N_NODES * 16 + blk - 1) / blk;
    const int ntiles = (N_NODES + SCAN_TILE - 1) / SCAN_TILE;
    const int ncnt = N_NODES * CNT_STRIDE;

    // ---- precompute: conversions + CSR
    {
        long long n4 = nf / 4;
        convert_f32_bf16<<<(int)((n4 + blk - 1) / blk), blk, 0, stream>>>(x, Xb, n4);
    }
    convert_w_t<128, 128><<<(128 * 128 + blk - 1) / blk, blk, 0, stream>>>(W1, Wt1);
    convert_w_t<128, 128><<<(128 * 128 + blk - 1) / blk, blk, 0, stream>>>(W2, Wt2);
    convert_w_t<128, 64><<<(128 * 64 + blk - 1) / blk, blk, 0, stream>>>(W3, Wt3);
    zero_ints<<<(ncnt + blk - 1) / blk, blk, 0, stream>>>(cnt, ncnt);
    rank_histogram<<<(N_EDGES + blk - 1) / blk, blk, 0, stream>>>(erow, cnt, rank);
    scan_tiles<<<ntiles, 256, 0, stream>>>(cnt, slocal, stsum, N_NODES);
    scan_finalize<<<ntiles, 256, 0, stream>>>(slocal, stsum, ntiles, rptr, N_NODES);
    fill_csr<<<(N_EDGES + blk - 1) / blk, blk, 0, stream>>>(erow, ecol, eval, rptr,
                                                            rank, cpack);

    // ---- Layer 1
    gemm_mfma<128, true><<<gemm_grid, 256, 0, stream>>>(Xb, Wt1, Ab, N_NODES, ntiles_g);
    aggregate_bf16<<<agg_grid, blk, 0, stream>>>(Ab, rptr, cpack, b1, Xb, N_NODES);

    // ---- Layer 2
    gemm_mfma<128, true><<<gemm_grid, 256, 0, stream>>>(Xb, Wt2, Ab, N_NODES, ntiles_g);
    aggregate_bf16<<<agg_grid, blk, 0, stream>>>(Ab, rptr, cpack, b2, Xb, N_NODES);

    // ---- Layer 3 (bf16 support, fp32 accumulate + fp32 out)
    gemm_mfma<64, true><<<gemm_grid, 256, 0, stream>>>(Xb, Wt3, Ab, N_NODES, ntiles_g);
    aggregate_bf16_64<<<agg_grid, blk, 0, stream>>>(Ab, rptr, cpack, b3, out, N_NODES);
}